// Round 7
// baseline (135099.060 us; speedup 1.0000x reference)
//
#include <hip/hip_runtime.h>

using u16 = unsigned short;
using u32 = unsigned int;

#define B_  4
#define NG_ 40962
#define NM_ 10242
#define E_  65536
#define NL_ 6

__device__ __forceinline__ float bf2f(u16 u) {
  union { float f; u32 i; } x; x.i = ((u32)u) << 16; return x.f;
}
__device__ __forceinline__ u16 f2bf(float f) {
  union { float f; u32 i; } x; x.f = f;
  u32 i = x.i;
  u32 r = (i + 0x7FFFu + ((i >> 16) & 1u)) >> 16;
  return (u16)r;
}
__device__ __forceinline__ float silu_f(float v) {
  float c = fminf(fmaxf(v, -88.f), 88.f);
  return c / (1.f + __expf(-c));
}
// flag-aware input read: flg==0 -> f32, flg==1 -> bf16
__device__ __forceinline__ float rdf(const void* p, long i, int flg) {
  return flg ? bf2f(((const u16*)p)[i]) : ((const float*)p)[i];
}

// ---------------- dtype detect: grid_g[0] == 1.0f as f32 word? -------------------------------
__global__ void detect_k(const u32* __restrict__ gg, int* __restrict__ flag) {
  if (threadIdx.x == 0) *flag = (gg[0] == 0x3F800000u) ? 0 : 1;
}

// ---------------- canonicalize one array to f32 ----------------------------------------------
__global__ __launch_bounds__(256) void cvt_k(const void* __restrict__ src, float* __restrict__ dst,
                                             long n, const int* __restrict__ flag) {
  int flg = *flag;
  long i = (long)blockIdx.x * 256 + threadIdx.x;
  if (i < n) dst[i] = rdf(src, i, flg);
}

// ---------------- canonicalize many small arrays ---------------------------------------------
struct CvtMany {
  const void* src[24];
  int off[24];
  int n[24];
  int cnt;
  float* dstbase;
  const int* flag;
};
__global__ __launch_bounds__(256) void cvt_many_k(CvtMany cm) {
  int e = blockIdx.y;
  if (e >= cm.cnt) return;
  int flg = *cm.flag;
  int i = blockIdx.x * 256 + threadIdx.x;
  if (i < cm.n[e]) cm.dstbase[cm.off[e] + i] = rdf(cm.src[e], i, flg);
}

// ---------------- weight transpose: src [K x 256] -> dst bf16 [256 x Kpad] (zero-padded) -----
__global__ void transpose_k(const void* __restrict__ src, u16* __restrict__ dst,
                            int K, int Kpad, long smat, long dmat, const int* __restrict__ flag) {
  int flg = *flag;
  long l = blockIdx.z;
  int idx = blockIdx.x * 256 + threadIdx.x;   // covers 256*Kpad
  int n = idx / Kpad;
  int k = idx - n * Kpad;
  if (n < 256)
    dst[l * dmat + (long)n * Kpad + k] =
        (k < K) ? f2bf(rdf(src, l * smat + (long)k * 256 + n, flg)) : (u16)0;
}

// ---------------- zero helper ----------------------------------------------------------------
__global__ __launch_bounds__(256) void zero_f32_k(float* __restrict__ p, long n4) {
  long i = (long)blockIdx.x * 256 + threadIdx.x;
  if (i < n4) ((float4*)p)[i] = (float4){0.f, 0.f, 0.f, 0.f};
}

// ---------------- pooling gathers (single batch) ---------------------------------------------
__global__ __launch_bounds__(256) void g2m_b_k(const u16* __restrict__ gpb, const int* __restrict__ idx,
                                               const float* __restrict__ wts, u16* __restrict__ outb) {
  int m = blockIdx.x, c = threadIdx.x;
  float a = 0.f;
  #pragma unroll 4
  for (int k = 0; k < 16; k++) {
    int gi = idx[m * 16 + k];
    a += wts[m * 16 + k] * bf2f(gpb[(long)gi * 256 + c]);
  }
  outb[(long)m * 256 + c] = f2bf(a);
}

__global__ __launch_bounds__(256) void m2g_b_k(const float* __restrict__ xb, const int* __restrict__ idx,
                                               const float* __restrict__ wts, u16* __restrict__ outb) {
  int gn = blockIdx.x, c = threadIdx.x;
  float a = 0.f;
  #pragma unroll
  for (int k = 0; k < 4; k++) {
    int mi = idx[gn * 4 + k];
    a += wts[gn * 4 + k] * xb[(long)mi * 256 + c];
  }
  outb[(long)gn * 256 + c] = f2bf(a);
}

// ---------------- naive GEMM: one block per output row ---------------------------------------
enum { A_DIRECT = 0, A_EDGE = 1, A_NODE1 = 2, A_GRID = 3, A_COMB = 4 };
enum { E_STORE = 0, E_LN_STORE = 1, E_RESID = 2, E_LN_SCATTER = 3, E_LN_DEC = 4 };

struct GemmP {
  const u16* A;        // direct/comb bf16 [M x K]
  const float* Ax;     // edge/node1: x master f32 [B*NM x 256]
  const float* Aagg;   // node1: agg f32
  const u16* Wt;       // [256 x Kpad] bf16 (N-major)
  const float* bias;   // [256] f32 or null
  const float* g;
  const float* beta;
  u16* Y;
  float* xf32;
  float* agg;
  const int* edst;
  const int* esrc;
  const float* ea;     // edge_attr f32 [E x 4]
  const float* mf;     // mesh_features f32 [NM x 3]
  const float* dw2;    // dec_w2 f32 [256 x 2]
  const float* db2;    // dec_b2 f32 [2]
  float* out2;         // FINAL OUTPUT: float32 (the reference's output dtype)
  // A_GRID params (canonical f32)
  const float* gin;
  const float* gw1;
  const float* gb1;
  const float* gg;
  const float* gbe;
  long rowoff;
  int K, Kpad;
};

template <int AM, int EM>
__global__ __launch_bounds__(256) void ngemm_k(GemmP p) {
  __shared__ float arow[544];
  __shared__ float reda[256];
  __shared__ float redb[256];
  const int c = threadIdx.x;
  const long R = blockIdx.x;

  // ---- build the A row in LDS (f32) ----
  if (AM == A_GRID) {
    long grow = p.rowoff + R;
    float in0 = p.gin[grow * 2], in1 = p.gin[grow * 2 + 1];
    float tv = in0 * p.gw1[c] + in1 * p.gw1[256 + c] + p.gb1[c];
    reda[c] = tv; redb[c] = tv * tv;
    __syncthreads();
    for (int s = 128; s > 0; s >>= 1) {
      if (c < s) { reda[c] += reda[c + s]; redb[c] += redb[c + s]; }
      __syncthreads();
    }
    float mu = reda[0] * (1.f / 256.f);
    float var = fmaxf(redb[0] * (1.f / 256.f) - mu * mu, 0.f);
    float rs = rsqrtf(var + 1e-5f);
    __syncthreads();
    arow[c] = silu_f((tv - mu) * rs * p.gg[c] + p.gbe[c]);
  } else if (AM == A_DIRECT) {
    for (int k = c; k < p.K; k += 256) arow[k] = bf2f(p.A[R * (long)p.K + k]);
  } else if (AM == A_COMB) {
    arow[c] = bf2f(p.A[R * 256 + c]);
    if (c < 3) arow[256 + c] = p.mf[(R % NM_) * 3 + c];
  } else if (AM == A_EDGE) {
    int b = (int)(R >> 16), e = (int)(R & 65535);
    int nd = p.edst[e], ns = p.esrc[e];
    arow[c]       = p.Ax[((long)(b * NM_ + nd)) * 256 + c];
    arow[256 + c] = p.Ax[((long)(b * NM_ + ns)) * 256 + c];
    if (c < 4) arow[512 + c] = p.ea[(long)e * 4 + c];
  } else { // A_NODE1
    arow[c]       = p.Ax[R * 256 + c];
    arow[256 + c] = p.Aagg[R * 256 + c];
  }
  __syncthreads();

  // ---- serial-K dot product: out col c ----
  float v = p.bias ? p.bias[c] : 0.f;
  const u16* wc = p.Wt + (long)c * p.Kpad;
  for (int k = 0; k < p.K; k++) v += arow[k] * bf2f(wc[k]);

  // ---- epilogue ----
  if (EM == E_STORE) { p.Y[R * 256 + c] = f2bf(v); return; }
  if (EM == E_RESID) { p.xf32[R * 256 + c] += v; return; }

  // block LN over the 256 outputs of this row
  __syncthreads();
  reda[c] = v; redb[c] = v * v;
  __syncthreads();
  for (int s = 128; s > 0; s >>= 1) {
    if (c < s) { reda[c] += reda[c + s]; redb[c] += redb[c + s]; }
    __syncthreads();
  }
  float mu = reda[0] * (1.f / 256.f);
  float var = fmaxf(redb[0] * (1.f / 256.f) - mu * mu, 0.f);
  float rs = rsqrtf(var + 1e-5f);
  float u = silu_f((v - mu) * rs * p.g[c] + p.beta[c]);

  if (EM == E_LN_STORE) { p.Y[R * 256 + c] = f2bf(u); return; }
  if (EM == E_LN_SCATTER) {
    int b = (int)(R >> 16), e = (int)(R & 65535);
    int dn = p.edst[e];
    atomicAdd(&p.agg[((long)(b * NM_ + dn)) * 256 + c], u);
    return;
  }
  // E_LN_DEC: fuse 256->2 GEMV, store FLOAT32 output
  __syncthreads();
  reda[c] = u * p.dw2[c * 2];
  redb[c] = u * p.dw2[c * 2 + 1];
  __syncthreads();
  for (int s = 128; s > 0; s >>= 1) {
    if (c < s) { reda[c] += reda[c + s]; redb[c] += redb[c + s]; }
    __syncthreads();
  }
  if (c == 0) {
    p.out2[R * 2]     = reda[0] + p.db2[0];
    p.out2[R * 2 + 1] = redb[0] + p.db2[1];
  }
}

// =================================================================================================
extern "C" void kernel_launch(void* const* d_in, const int* in_sizes, int n_in,
                              void* d_out, int out_size, void* d_ws, size_t ws_size,
                              hipStream_t stream) {
  const void* grid_input    = d_in[0];
  const void* mesh_features = d_in[1];
  const void* edge_attr     = d_in[2];
  const void* g2m_w         = d_in[3];
  const void* m2g_w         = d_in[4];
  const int* edge_index     = (const int*)d_in[5];
  const int* g2m_i          = (const int*)d_in[6];
  const int* m2g_i          = (const int*)d_in[7];
  const void* grid_w1 = d_in[8];
  const void* grid_b1 = d_in[9];
  const void* grid_g  = d_in[10];
  const void* grid_be = d_in[11];
  const void* grid_w2 = d_in[12];
  const void* grid_b2 = d_in[13];
  const void* comb_w1 = d_in[14];
  const void* comb_b1 = d_in[15];
  const void* comb_g  = d_in[16];
  const void* comb_be = d_in[17];
  const void* comb_w2 = d_in[18];
  const void* comb_b2 = d_in[19];
  const void* edge_w  = d_in[20];
  const void* edge_b  = d_in[21];
  const void* edge_g  = d_in[22];
  const void* edge_be = d_in[23];
  const void* node_w1 = d_in[24];
  const void* node_b1 = d_in[25];
  const void* node_g  = d_in[26];
  const void* node_be = d_in[27];
  const void* node_w2 = d_in[28];
  const void* node_b2 = d_in[29];
  const void* dec_w1  = d_in[30];
  const void* dec_b1  = d_in[31];
  const void* dec_g   = d_in[32];
  const void* dec_be  = d_in[33];
  const void* dec_w2  = d_in[34];
  const void* dec_b2  = d_in[35];
  (void)in_sizes; (void)n_in; (void)out_size; (void)ws_size;

  const long BNG = (long)B_ * NG_;  // 163848
  const long BNM = (long)B_ * NM_;  // 40968
  const long BE  = (long)B_ * E_;   // 262144

  char* ws = (char*)d_ws;
  size_t off = 0;
  auto al = [&](size_t n) -> char* {
    char* pp = ws + off;
    off += (n + 255) & ~(size_t)255;
    return pp;
  };

  int* dflag = (int*)al(256);
  // transposed weights (~4.6 MB, bf16)
  u16* wt_grid_w2 = (u16*)al(256 * 256 * 2);
  u16* wt_comb_w1 = (u16*)al(256 * 288 * 2);
  u16* wt_comb_w2 = (u16*)al(256 * 256 * 2);
  u16* wt_dec_w1  = (u16*)al(256 * 256 * 2);
  u16* wt_edge    = (u16*)al((size_t)NL_ * 256 * 544 * 2);
  u16* wt_node1   = (u16*)al((size_t)NL_ * 256 * 512 * 2);
  u16* wt_node2   = (u16*)al((size_t)NL_ * 256 * 256 * 2);
  // canonical f32 inputs (~5 MB)
  float* c_gin  = (float*)al((size_t)BNG * 2 * 4);
  float* c_mf   = (float*)al((size_t)NM_ * 3 * 4);
  float* c_ea   = (float*)al((size_t)E_ * 4 * 4);
  float* c_g2mw = (float*)al((size_t)NM_ * 16 * 4);
  float* c_m2gw = (float*)al((size_t)NG_ * 4 * 4);
  float* varena = (float*)al(16384 * 4);
  // region A (21 MB): gp_b / t2 / glat_b
  char* regA = al((size_t)BNM * 256 * 2);
  u16* gp_b   = (u16*)regA;
  u16* t2     = (u16*)regA;
  u16* glat_b = (u16*)regA;
  // region B (42 MB): pooled (bf16) then agg (f32)
  char* regB = al((size_t)BNM * 256 * 4);
  u16* pooled = (u16*)regB;
  float* agg  = (float*)regB;
  // x master (f32, 42 MB)
  float* xf32 = (float*)al((size_t)BNM * 256 * 4);
  // total ~115 MB

  // varena offsets (floats)
  const int O_GB1 = 0, O_GG = 256, O_GBE = 512, O_GB2 = 768;
  const int O_CB1 = 1024, O_CG = 1280, O_CBE = 1536, O_CB2 = 1792;
  const int O_DB1 = 2048, O_DG = 2304, O_DBE = 2560, O_DB2 = 2816, O_DW2 = 2880;
  const int O_EB = 3584, O_EG = 5120, O_EBE = 6656;
  const int O_NB1 = 8192, O_NG = 9728, O_NBE = 11264, O_NB2 = 12800;
  const int O_GW1 = 14336;

  // ---- dtype detect + canonicalize ----
  detect_k<<<dim3(1), 64, 0, stream>>>((const u32*)grid_g, dflag);
  cvt_k<<<dim3((int)((BNG * 2 + 255) / 256)), 256, 0, stream>>>(grid_input, c_gin, BNG * 2, dflag);
  cvt_k<<<dim3((NM_ * 3 + 255) / 256), 256, 0, stream>>>(mesh_features, c_mf, (long)NM_ * 3, dflag);
  cvt_k<<<dim3((E_ * 4 + 255) / 256), 256, 0, stream>>>(edge_attr, c_ea, (long)E_ * 4, dflag);
  cvt_k<<<dim3((NM_ * 16 + 255) / 256), 256, 0, stream>>>(g2m_w, c_g2mw, (long)NM_ * 16, dflag);
  cvt_k<<<dim3((NG_ * 4 + 255) / 256), 256, 0, stream>>>(m2g_w, c_m2gw, (long)NG_ * 4, dflag);
  {
    CvtMany cm{};
    cm.dstbase = varena; cm.flag = dflag;
    int i = 0;
    auto add = [&](const void* s, int o, int n) { cm.src[i] = s; cm.off[i] = o; cm.n[i] = n; i++; };
    add(grid_b1, O_GB1, 256); add(grid_g, O_GG, 256); add(grid_be, O_GBE, 256); add(grid_b2, O_GB2, 256);
    add(comb_b1, O_CB1, 256); add(comb_g, O_CG, 256); add(comb_be, O_CBE, 256); add(comb_b2, O_CB2, 256);
    add(dec_b1, O_DB1, 256);  add(dec_g, O_DG, 256);  add(dec_be, O_DBE, 256);  add(dec_b2, O_DB2, 2);
    add(dec_w2, O_DW2, 512);
    add(edge_b, O_EB, NL_ * 256); add(edge_g, O_EG, NL_ * 256); add(edge_be, O_EBE, NL_ * 256);
    add(node_b1, O_NB1, NL_ * 256); add(node_g, O_NG, NL_ * 256); add(node_be, O_NBE, NL_ * 256);
    add(node_b2, O_NB2, NL_ * 256);
    add(grid_w1, O_GW1, 512);
    cm.cnt = i;
    cvt_many_k<<<dim3(6, cm.cnt), 256, 0, stream>>>(cm);
  }

  // ---- weight transposes (flag-aware src, bf16 N-major out) ----
  transpose_k<<<dim3(256, 1, 1), 256, 0, stream>>>(grid_w2, wt_grid_w2, 256, 256, 0, 0, dflag);
  transpose_k<<<dim3(288, 1, 1), 256, 0, stream>>>(comb_w1, wt_comb_w1, 259, 288, 0, 0, dflag);
  transpose_k<<<dim3(256, 1, 1), 256, 0, stream>>>(comb_w2, wt_comb_w2, 256, 256, 0, 0, dflag);
  transpose_k<<<dim3(256, 1, 1), 256, 0, stream>>>(dec_w1,  wt_dec_w1,  256, 256, 0, 0, dflag);
  transpose_k<<<dim3(544, 1, NL_), 256, 0, stream>>>(edge_w,  wt_edge,  516, 544, (long)516 * 256, (long)256 * 544, dflag);
  transpose_k<<<dim3(512, 1, NL_), 256, 0, stream>>>(node_w1, wt_node1, 512, 512, (long)512 * 256, (long)256 * 512, dflag);
  transpose_k<<<dim3(256, 1, NL_), 256, 0, stream>>>(node_w2, wt_node2, 256, 256, (long)256 * 256, (long)256 * 256, dflag);

  // ---- grid encoder + g2m pooling, streamed per batch through gp_b ----
  for (int b = 0; b < B_; b++) {
    GemmP p{}; p.Wt = wt_grid_w2; p.bias = varena + O_GB2; p.Y = gp_b;
    p.gin = c_gin; p.gw1 = varena + O_GW1; p.gb1 = varena + O_GB1;
    p.gg = varena + O_GG; p.gbe = varena + O_GBE;
    p.rowoff = (long)b * NG_;
    p.K = 256; p.Kpad = 256;
    ngemm_k<A_GRID, E_STORE><<<dim3(NG_), 256, 0, stream>>>(p);
    g2m_b_k<<<dim3(NM_), 256, 0, stream>>>(gp_b, g2m_i, c_g2mw, pooled + (long)b * NM_ * 256);
  }

  // ---- comb MLP ----
  {
    GemmP p{}; p.A = pooled; p.mf = c_mf; p.Wt = wt_comb_w1; p.bias = varena + O_CB1;
    p.g = varena + O_CG; p.beta = varena + O_CBE; p.Y = t2; p.K = 259; p.Kpad = 288;
    ngemm_k<A_COMB, E_LN_STORE><<<dim3((int)BNM), 256, 0, stream>>>(p);
  }
  const long n4 = BNM * 256 / 4;
  zero_f32_k<<<dim3((int)((n4 + 255) / 256)), 256, 0, stream>>>(xf32, n4);
  {
    GemmP p{}; p.A = t2; p.Wt = wt_comb_w2; p.bias = varena + O_CB2; p.xf32 = xf32;
    p.K = 256; p.Kpad = 256;
    ngemm_k<A_DIRECT, E_RESID><<<dim3((int)BNM), 256, 0, stream>>>(p);
  }

  // ---- message-passing layers ----
  for (int l = 0; l < NL_; l++) {
    zero_f32_k<<<dim3((int)((n4 + 255) / 256)), 256, 0, stream>>>(agg, n4);
    {
      GemmP p{}; p.Ax = xf32; p.Wt = wt_edge + (size_t)l * 256 * 544;
      p.bias = varena + O_EB + l * 256; p.g = varena + O_EG + l * 256; p.beta = varena + O_EBE + l * 256;
      p.agg = agg; p.edst = edge_index + E_; p.esrc = edge_index; p.ea = c_ea;
      p.K = 516; p.Kpad = 544;
      ngemm_k<A_EDGE, E_LN_SCATTER><<<dim3((int)BE), 256, 0, stream>>>(p);
    }
    {
      GemmP p{}; p.Ax = xf32; p.Aagg = agg; p.Wt = wt_node1 + (size_t)l * 256 * 512;
      p.bias = varena + O_NB1 + l * 256; p.g = varena + O_NG + l * 256; p.beta = varena + O_NBE + l * 256;
      p.Y = t2; p.K = 512; p.Kpad = 512;
      ngemm_k<A_NODE1, E_LN_STORE><<<dim3((int)BNM), 256, 0, stream>>>(p);
    }
    {
      GemmP p{}; p.A = t2; p.Wt = wt_node2 + (size_t)l * 256 * 256;
      p.bias = varena + O_NB2 + l * 256; p.xf32 = xf32;
      p.K = 256; p.Kpad = 256;
      ngemm_k<A_DIRECT, E_RESID><<<dim3((int)BNM), 256, 0, stream>>>(p);
    }
  }

  // ---- m2g pooling + decoder (dec2 fused), streamed per batch; FLOAT32 output ----
  for (int b = 0; b < B_; b++) {
    m2g_b_k<<<dim3(NG_), 256, 0, stream>>>(xf32 + (long)b * NM_ * 256, m2g_i, c_m2gw, glat_b);
    GemmP p{}; p.A = glat_b; p.Wt = wt_dec_w1; p.bias = varena + O_DB1;
    p.g = varena + O_DG; p.beta = varena + O_DBE;
    p.dw2 = varena + O_DW2; p.db2 = varena + O_DB2;
    p.out2 = (float*)d_out + (long)b * NG_ * 2;
    p.K = 256; p.Kpad = 256;
    ngemm_k<A_DIRECT, E_LN_DEC><<<dim3(NG_), 256, 0, stream>>>(p);
  }
}

// Round 8
// 3421.898 us; speedup vs baseline: 39.4807x; 39.4807x over previous
//
#include <hip/hip_runtime.h>

using u16 = unsigned short;
using u32 = unsigned int;

typedef __attribute__((ext_vector_type(8))) short short8;
typedef __attribute__((ext_vector_type(4))) float floatx4;

#define B_  4
#define NG_ 40962
#define NM_ 10242
#define E_  65536
#define NL_ 6

__device__ __forceinline__ float bf2f(u16 u) {
  union { float f; u32 i; } x; x.i = ((u32)u) << 16; return x.f;
}
__device__ __forceinline__ u16 f2bf(float f) {
  union { float f; u32 i; } x; x.f = f;
  u32 i = x.i;
  u32 r = (i + 0x7FFFu + ((i >> 16) & 1u)) >> 16;
  return (u16)r;
}
__device__ __forceinline__ float silu_f(float v) {
  float c = fminf(fmaxf(v, -88.f), 88.f);
  return c / (1.f + __expf(-c));
}
__device__ __forceinline__ float satf(float v) {
  return fminf(fmaxf(v, -65504.f), 65504.f);
}
// flag-aware input read: flg==0 -> f32, flg==1 -> bf16
__device__ __forceinline__ float rdf(const void* p, long i, int flg) {
  return flg ? bf2f(((const u16*)p)[i]) : ((const float*)p)[i];
}

// ---------------- dtype detect ---------------------------------------------------------------
__global__ void detect_k(const u32* __restrict__ gg, int* __restrict__ flag) {
  if (threadIdx.x == 0) *flag = (gg[0] == 0x3F800000u) ? 0 : 1;
}

// ---------------- canonicalize one array to f32 ----------------------------------------------
__global__ __launch_bounds__(256) void cvt_k(const void* __restrict__ src, float* __restrict__ dst,
                                             long n, const int* __restrict__ flag) {
  int flg = *flag;
  long i = (long)blockIdx.x * 256 + threadIdx.x;
  if (i < n) dst[i] = rdf(src, i, flg);
}

// ---------------- canonicalize many small arrays ---------------------------------------------
struct CvtMany {
  const void* src[24];
  int off[24];
  int n[24];
  int cnt;
  float* dstbase;
  const int* flag;
};
__global__ __launch_bounds__(256) void cvt_many_k(CvtMany cm) {
  int e = blockIdx.y;
  if (e >= cm.cnt) return;
  int flg = *cm.flag;
  int i = blockIdx.x * 256 + threadIdx.x;
  if (i < cm.n[e]) cm.dstbase[cm.off[e] + i] = rdf(cm.src[e], i, flg);
}

// ---------------- weight transpose: src [K x 256] -> dst bf16 [256 x Kpad] (zero-padded) -----
__global__ void transpose_k(const void* __restrict__ src, u16* __restrict__ dst,
                            int K, int Kpad, long smat, long dmat, const int* __restrict__ flag) {
  int flg = *flag;
  long l = blockIdx.z;
  int idx = blockIdx.x * 256 + threadIdx.x;   // covers 256*Kpad
  int n = idx / Kpad;
  int k = idx - n * Kpad;
  if (n < 256)
    dst[l * dmat + (long)n * Kpad + k] =
        (k < K) ? f2bf(rdf(src, l * smat + (long)k * 256 + n, flg)) : (u16)0;
}

// ---------------- zero helper ----------------------------------------------------------------
__global__ __launch_bounds__(256) void zero_f32_k(float* __restrict__ p, long n4) {
  long i = (long)blockIdx.x * 256 + threadIdx.x;
  if (i < n4) ((float4*)p)[i] = (float4){0.f, 0.f, 0.f, 0.f};
}

// ---------------- grid encoder LN stats (canonical f32 in) -----------------------------------
__global__ __launch_bounds__(256) void grid_stats_k(const float* __restrict__ gin,
                                                    const float* __restrict__ w1,
                                                    const float* __restrict__ b1,
                                                    float* __restrict__ stats, int M) {
  int row = blockIdx.x * 4 + (threadIdx.x >> 6);
  int lane = threadIdx.x & 63;
  if (row >= M) return;
  float in0 = gin[(long)row * 2], in1 = gin[(long)row * 2 + 1];
  float s = 0.f, s2 = 0.f;
  #pragma unroll
  for (int j = 0; j < 4; j++) {
    int c = lane * 4 + j;
    float x = in0 * w1[c] + in1 * w1[256 + c] + b1[c];
    s += x; s2 += x * x;
  }
  #pragma unroll
  for (int o = 1; o < 64; o <<= 1) { s += __shfl_xor(s, o); s2 += __shfl_xor(s2, o); }
  if (lane == 0) {
    float mu = s * (1.f / 256.f);
    float var = fmaxf(s2 * (1.f / 256.f) - mu * mu, 0.f);
    stats[row * 2] = mu;
    stats[row * 2 + 1] = rsqrtf(var + 1e-5f);
  }
}

// ---------------- pooling gathers (single batch) ---------------------------------------------
__global__ __launch_bounds__(256) void g2m_b_k(const u16* __restrict__ gpb, const int* __restrict__ idx,
                                               const float* __restrict__ wts, u16* __restrict__ outb) {
  int m = blockIdx.x, c = threadIdx.x;
  float a = 0.f;
  #pragma unroll 4
  for (int k = 0; k < 16; k++) {
    int gi = idx[m * 16 + k];
    a += wts[m * 16 + k] * bf2f(gpb[(long)gi * 256 + c]);
  }
  outb[(long)m * 256 + c] = f2bf(a);
}

__global__ __launch_bounds__(256) void m2g_b_k(const float* __restrict__ xb, const int* __restrict__ idx,
                                               const float* __restrict__ wts, u16* __restrict__ outb) {
  int gn = blockIdx.x, c = threadIdx.x;
  float a = 0.f;
  #pragma unroll
  for (int k = 0; k < 4; k++) {
    int mi = idx[gn * 4 + k];
    a += wts[gn * 4 + k] * xb[(long)mi * 256 + c];
  }
  outb[(long)gn * 256 + c] = f2bf(a);
}

// ---------------- the MFMA GEMM template -----------------------------------------------------
enum { A_DIRECT = 0, A_EDGE = 1, A_NODE1 = 2, A_GRID = 3, A_COMB = 4 };
enum { E_STORE = 0, E_LN_STORE = 1, E_RESID = 2, E_LN_SCATTER = 3, E_LN_DEC = 4 };

struct GemmP {
  const u16* A;        // direct/comb bf16 [M x K]
  const float* Ax;     // edge/node1: x master f32 [B*NM x 256]
  const float* Aagg;   // node1: agg f32
  const u16* Wt;       // [256 x Kpad] bf16 (N-major)
  const float* bias;   // [256] f32 or null
  const float* g;
  const float* beta;
  u16* Y;
  float* xf32;
  float* agg;
  const int* edst;
  const int* esrc;
  const float* ea;     // edge_attr f32 [E x 4]
  const float* mf;     // mesh_features f32 [NM x 3]
  const float* dw2;    // dec_w2 f32 [256 x 2]
  const float* db2;    // dec_b2 f32 [2]
  float* out2;         // FINAL OUTPUT: float32
  // A_GRID params (canonical f32)
  const float* gin;
  const float* gw1;
  const float* gb1;
  const float* gg;
  const float* gbe;
  const float* stats;
  long rowoff;
  int M, K, Kpad;
};

__device__ __forceinline__ void cvt8(const float* __restrict__ src, u16* __restrict__ dst) {
  float4 f0 = ((const float4*)src)[0];
  float4 f1 = ((const float4*)src)[1];
  dst[0] = f2bf(f0.x); dst[1] = f2bf(f0.y); dst[2] = f2bf(f0.z); dst[3] = f2bf(f0.w);
  dst[4] = f2bf(f1.x); dst[5] = f2bf(f1.y); dst[6] = f2bf(f1.z); dst[7] = f2bf(f1.w);
}

template <int AM, int EM>
__global__ __launch_bounds__(256, 2) void gemm_k(GemmP p) {
  __shared__ __align__(16) u16 Asm[64 * 40];
  __shared__ __align__(16) u16 Bsm[256 * 40];
  __shared__ float part_s [64 * 65];
  __shared__ float part_s2[64 * 65];
  __shared__ float stats_sm[64][2];

  const int t = threadIdx.x;
  const int lane = t & 63, w = t >> 6;
  const int l15 = lane & 15, q = lane >> 4;
  const long blk = blockIdx.x;

  const int lr = t >> 2;          // 0..63 (tile row)
  const int c8 = (t & 3) * 8;     // 0/8/16/24 within the 32-wide k chunk
  const long gr_s = blk * 64 + lr;

  int bb = 0, ee = 0, nd = 0, ns = 0, cmn = 0;
  if (AM == A_EDGE) {
    bb = (int)(gr_s >> 16);
    ee = (int)(gr_s & 65535);
    nd = p.edst[ee];
    ns = p.esrc[ee];
  }
  if (AM == A_COMB) cmn = (int)(gr_s % NM_);
  float gin0 = 0.f, gin1 = 0.f, gmu = 0.f, grs = 0.f;
  if (AM == A_GRID) {
    if (gr_s < p.M) {
      long grow = p.rowoff + gr_s;
      gin0 = p.gin[grow * 2];
      gin1 = p.gin[grow * 2 + 1];
      gmu = p.stats[grow * 2];
      grs = p.stats[grow * 2 + 1];
    }
  }

  floatx4 acc[4][4];
  #pragma unroll
  for (int i = 0; i < 4; i++)
    #pragma unroll
    for (int j = 0; j < 4; j++) acc[i][j] = (floatx4){0.f, 0.f, 0.f, 0.f};

  const int nk = p.Kpad >> 5;
  for (int ks = 0; ks < nk; ks++) {
    const int k0 = ks << 5;
    const int kc = k0 + c8;

    // ---- load A chunk into regs ----
    union { uint4 v; u16 s[8]; } av;
    av.v = (uint4){0u, 0u, 0u, 0u};
    if (AM == A_DIRECT) {
      if (gr_s < p.M) av.v = *(const uint4*)(p.A + gr_s * (long)p.K + kc);
    } else if (AM == A_EDGE) {
      if (kc < 256) {
        cvt8(p.Ax + ((long)(bb * NM_ + nd)) * 256 + kc, av.s);
      } else if (kc < 512) {
        cvt8(p.Ax + ((long)(bb * NM_ + ns)) * 256 + (kc - 256), av.s);
      } else {
        #pragma unroll
        for (int j = 0; j < 8; j++) {
          int qq = kc - 512 + j;
          av.s[j] = (qq < 4) ? f2bf(p.ea[(long)ee * 4 + qq]) : (u16)0;
        }
      }
    } else if (AM == A_NODE1) {
      if (gr_s < p.M) {
        if (kc < 256) cvt8(p.Ax + gr_s * 256 + kc, av.s);
        else          cvt8(p.Aagg + gr_s * 256 + (kc - 256), av.s);
      }
    } else if (AM == A_COMB) {
      if (gr_s < p.M) {
        if (kc < 256) {
          av.v = *(const uint4*)(p.A + gr_s * 256 + kc);
        } else {
          #pragma unroll
          for (int j = 0; j < 8; j++) {
            int c = kc - 256 + j;
            av.s[j] = (c < 3) ? f2bf(p.mf[(long)cmn * 3 + c]) : (u16)0;
          }
        }
      }
    } else { // A_GRID: recompute silu(ln(gin@w1+b1)) on the fly
      if (gr_s < p.M) {
        #pragma unroll
        for (int j = 0; j < 8; j++) {
          int c = kc + j;
          float tv = gin0 * p.gw1[c] + gin1 * p.gw1[256 + c] + p.gb1[c];
          float v = (tv - gmu) * grs * p.gg[c] + p.gbe[c];
          av.s[j] = f2bf(silu_f(v));
        }
      }
    }

    __syncthreads();  // prior iteration's LDS reads done
    *(uint4*)(Asm + lr * 40 + c8) = av.v;

    // ---- stage B (weights, N-major) ----
    {
      const uint4* wp = (const uint4*)(p.Wt + (long)t * p.Kpad + k0);
      uint4 b0 = wp[0], b1 = wp[1], b2 = wp[2], b3 = wp[3];
      uint4* bs = (uint4*)(Bsm + t * 40);
      bs[0] = b0; bs[1] = b1; bs[2] = b2; bs[3] = b3;
    }
    __syncthreads();

    // ---- MFMA ----
    short8 af[4], bf[4];
    #pragma unroll
    for (int i = 0; i < 4; i++)
      af[i] = *(const short8*)(Asm + (i * 16 + l15) * 40 + q * 8);
    #pragma unroll
    for (int j = 0; j < 4; j++)
      bf[j] = *(const short8*)(Bsm + (w * 64 + j * 16 + l15) * 40 + q * 8);
    #pragma unroll
    for (int i = 0; i < 4; i++)
      #pragma unroll
      for (int j = 0; j < 4; j++)
        acc[i][j] = __builtin_amdgcn_mfma_f32_16x16x32_bf16(af[i], bf[j], acc[i][j], 0, 0, 0);
  }

  // ================= epilogue =================
  const int colb = w * 64 + l15;  // + j*16
  float bcol[4];
  #pragma unroll
  for (int j = 0; j < 4; j++) bcol[j] = p.bias ? p.bias[colb + j * 16] : 0.f;

  if (EM == E_STORE || EM == E_RESID) {
    #pragma unroll
    for (int i = 0; i < 4; i++) {
      #pragma unroll
      for (int r = 0; r < 4; r++) {
        long gr = blk * 64 + i * 16 + q * 4 + r;
        if (gr >= p.M) continue;
        long rowo = gr * 256 + colb;
        #pragma unroll
        for (int j = 0; j < 4; j++) {
          float v = acc[i][j][r] + bcol[j];
          long o = rowo + j * 16;
          if (EM == E_STORE) {
            p.Y[o] = f2bf(v);
          } else { // E_RESID: xf32 += h
            p.xf32[o] = satf(p.xf32[o] + v);
          }
        }
      }
    }
    return;
  }

  // ---- LN modes: phase 1 — add bias (saturating), per-lane partials to LDS ----
  #pragma unroll
  for (int i = 0; i < 4; i++) {
    #pragma unroll
    for (int r = 0; r < 4; r++) {
      float s = 0.f, s2 = 0.f;
      #pragma unroll
      for (int j = 0; j < 4; j++) {
        float v = satf(acc[i][j][r] + bcol[j]);
        acc[i][j][r] = v;
        s += v; s2 += v * v;
      }
      int ml = i * 16 + q * 4 + r;
      part_s [ml * 65 + w * 16 + l15] = s;
      part_s2[ml * 65 + w * 16 + l15] = s2;
    }
  }
  __syncthreads();

  // ---- phase 2: 64 threads compute row stats ----
  if (t < 64) {
    float s = 0.f, s2 = 0.f;
    #pragma unroll 8
    for (int c = 0; c < 64; c++) { s += part_s[t * 65 + c]; s2 += part_s2[t * 65 + c]; }
    float mu = s * (1.f / 256.f);
    float var = fmaxf(s2 * (1.f / 256.f) - mu * mu, 0.f);
    stats_sm[t][0] = mu;
    stats_sm[t][1] = rsqrtf(var + 1e-5f);
  }
  __syncthreads();

  float gcol[4], becol[4];
  #pragma unroll
  for (int j = 0; j < 4; j++) { gcol[j] = p.g[colb + j * 16]; becol[j] = p.beta[colb + j * 16]; }

  if (EM == E_LN_STORE) {
    #pragma unroll
    for (int i = 0; i < 4; i++) {
      #pragma unroll
      for (int r = 0; r < 4; r++) {
        int ml = i * 16 + q * 4 + r;
        long gr = blk * 64 + ml;
        if (gr >= p.M) continue;
        float mu = stats_sm[ml][0], rs = stats_sm[ml][1];
        long rowo = gr * 256 + colb;
        #pragma unroll
        for (int j = 0; j < 4; j++) {
          float v = (acc[i][j][r] - mu) * rs * gcol[j] + becol[j];
          p.Y[rowo + j * 16] = f2bf(silu_f(v));
        }
      }
    }
  } else if (EM == E_LN_SCATTER) {
    #pragma unroll
    for (int i = 0; i < 4; i++) {
      #pragma unroll
      for (int r = 0; r < 4; r++) {
        int ml = i * 16 + q * 4 + r;
        long gr = blk * 64 + ml;
        if (gr >= p.M) continue;
        float mu = stats_sm[ml][0], rs = stats_sm[ml][1];
        int b2 = (int)(gr >> 16);
        int e2 = (int)(gr & 65535);
        int dn = p.edst[e2];
        long base = ((long)(b2 * NM_ + dn)) * 256 + colb;
        #pragma unroll
        for (int j = 0; j < 4; j++) {
          float v = (acc[i][j][r] - mu) * rs * gcol[j] + becol[j];
          atomicAdd(&p.agg[base + j * 16], silu_f(v));
        }
      }
    }
  } else { // E_LN_DEC: fuse tiny 256->2 GEMV, store FLOAT32
    #pragma unroll
    for (int i = 0; i < 4; i++) {
      #pragma unroll
      for (int r = 0; r < 4; r++) {
        int ml = i * 16 + q * 4 + r;
        float mu = stats_sm[ml][0], rs = stats_sm[ml][1];
        float d0 = 0.f, d1 = 0.f;
        #pragma unroll
        for (int j = 0; j < 4; j++) {
          int col = colb + j * 16;
          float v = silu_f((acc[i][j][r] - mu) * rs * gcol[j] + becol[j]);
          d0 += v * p.dw2[col * 2];
          d1 += v * p.dw2[col * 2 + 1];
        }
        part_s [ml * 65 + w * 16 + l15] = d0;
        part_s2[ml * 65 + w * 16 + l15] = d1;
      }
    }
    __syncthreads();
    if (t < 64) {
      long gr = blk * 64 + t;
      if (gr < p.M) {
        float y0 = 0.f, y1 = 0.f;
        #pragma unroll 8
        for (int c = 0; c < 64; c++) { y0 += part_s[t * 65 + c]; y1 += part_s2[t * 65 + c]; }
        p.out2[gr * 2]     = y0 + p.db2[0];
        p.out2[gr * 2 + 1] = y1 + p.db2[1];
      }
    }
  }
}

// =================================================================================================
extern "C" void kernel_launch(void* const* d_in, const int* in_sizes, int n_in,
                              void* d_out, int out_size, void* d_ws, size_t ws_size,
                              hipStream_t stream) {
  const void* grid_input    = d_in[0];
  const void* mesh_features = d_in[1];
  const void* edge_attr     = d_in[2];
  const void* g2m_w         = d_in[3];
  const void* m2g_w         = d_in[4];
  const int* edge_index     = (const int*)d_in[5];
  const int* g2m_i          = (const int*)d_in[6];
  const int* m2g_i          = (const int*)d_in[7];
  const void* grid_w1 = d_in[8];
  const void* grid_b1 = d_in[9];
  const void* grid_g  = d_in[10];
  const void* grid_be = d_in[11];
  const void* grid_w2 = d_in[12];
  const void* grid_b2 = d_in[13];
  const void* comb_w1 = d_in[14];
  const void* comb_b1 = d_in[15];
  const void* comb_g  = d_in[16];
  const void* comb_be = d_in[17];
  const void* comb_w2 = d_in[18];
  const void* comb_b2 = d_in[19];
  const void* edge_w  = d_in[20];
  const void* edge_b  = d_in[21];
  const void* edge_g  = d_in[22];
  const void* edge_be = d_in[23];
  const void* node_w1 = d_in[24];
  const void* node_b1 = d_in[25];
  const void* node_g  = d_in[26];
  const void* node_be = d_in[27];
  const void* node_w2 = d_in[28];
  const void* node_b2 = d_in[29];
  const void* dec_w1  = d_in[30];
  const void* dec_b1  = d_in[31];
  const void* dec_g   = d_in[32];
  const void* dec_be  = d_in[33];
  const void* dec_w2  = d_in[34];
  const void* dec_b2  = d_in[35];
  (void)in_sizes; (void)n_in; (void)out_size; (void)ws_size;

  const long BNG = (long)B_ * NG_;  // 163848
  const long BNM = (long)B_ * NM_;  // 40968
  const long BE  = (long)B_ * E_;   // 262144

  char* ws = (char*)d_ws;
  size_t off = 0;
  auto al = [&](size_t n) -> char* {
    char* pp = ws + off;
    off += (n + 255) & ~(size_t)255;
    return pp;
  };

  int* dflag = (int*)al(256);
  // transposed weights (~4.6 MB, bf16)
  u16* wt_grid_w2 = (u16*)al(256 * 256 * 2);
  u16* wt_comb_w1 = (u16*)al(256 * 288 * 2);
  u16* wt_comb_w2 = (u16*)al(256 * 256 * 2);
  u16* wt_dec_w1  = (u16*)al(256 * 256 * 2);
  u16* wt_edge    = (u16*)al((size_t)NL_ * 256 * 544 * 2);
  u16* wt_node1   = (u16*)al((size_t)NL_ * 256 * 512 * 2);
  u16* wt_node2   = (u16*)al((size_t)NL_ * 256 * 256 * 2);
  // canonical f32 inputs (~5 MB)
  float* c_gin  = (float*)al((size_t)BNG * 2 * 4);
  float* c_mf   = (float*)al((size_t)NM_ * 3 * 4);
  float* c_ea   = (float*)al((size_t)E_ * 4 * 4);
  float* c_g2mw = (float*)al((size_t)NM_ * 16 * 4);
  float* c_m2gw = (float*)al((size_t)NG_ * 4 * 4);
  float* varena = (float*)al(16384 * 4);
  float* gstats = (float*)al((size_t)BNG * 2 * 4);
  // region A (21 MB): gp_b / t2 / glat_b
  char* regA = al((size_t)BNM * 256 * 2);
  u16* gp_b   = (u16*)regA;
  u16* t2     = (u16*)regA;
  u16* glat_b = (u16*)regA;
  // region B (42 MB): pooled (bf16) then agg (f32)
  char* regB = al((size_t)BNM * 256 * 4);
  u16* pooled = (u16*)regB;
  float* agg  = (float*)regB;
  // x master (f32, 42 MB)
  float* xf32 = (float*)al((size_t)BNM * 256 * 4);
  // total ~119 MB

  // varena offsets (floats)
  const int O_GB1 = 0, O_GG = 256, O_GBE = 512, O_GB2 = 768;
  const int O_CB1 = 1024, O_CG = 1280, O_CBE = 1536, O_CB2 = 1792;
  const int O_DB1 = 2048, O_DG = 2304, O_DBE = 2560, O_DB2 = 2816, O_DW2 = 2880;
  const int O_EB = 3584, O_EG = 5120, O_EBE = 6656;
  const int O_NB1 = 8192, O_NG = 9728, O_NBE = 11264, O_NB2 = 12800;
  const int O_GW1 = 14336;

  // ---- dtype detect + canonicalize ----
  detect_k<<<dim3(1), 64, 0, stream>>>((const u32*)grid_g, dflag);
  cvt_k<<<dim3((int)((BNG * 2 + 255) / 256)), 256, 0, stream>>>(grid_input, c_gin, BNG * 2, dflag);
  cvt_k<<<dim3((NM_ * 3 + 255) / 256), 256, 0, stream>>>(mesh_features, c_mf, (long)NM_ * 3, dflag);
  cvt_k<<<dim3((E_ * 4 + 255) / 256), 256, 0, stream>>>(edge_attr, c_ea, (long)E_ * 4, dflag);
  cvt_k<<<dim3((NM_ * 16 + 255) / 256), 256, 0, stream>>>(g2m_w, c_g2mw, (long)NM_ * 16, dflag);
  cvt_k<<<dim3((NG_ * 4 + 255) / 256), 256, 0, stream>>>(m2g_w, c_m2gw, (long)NG_ * 4, dflag);
  {
    CvtMany cm{};
    cm.dstbase = varena; cm.flag = dflag;
    int i = 0;
    auto add = [&](const void* s, int o, int n) { cm.src[i] = s; cm.off[i] = o; cm.n[i] = n; i++; };
    add(grid_b1, O_GB1, 256); add(grid_g, O_GG, 256); add(grid_be, O_GBE, 256); add(grid_b2, O_GB2, 256);
    add(comb_b1, O_CB1, 256); add(comb_g, O_CG, 256); add(comb_be, O_CBE, 256); add(comb_b2, O_CB2, 256);
    add(dec_b1, O_DB1, 256);  add(dec_g, O_DG, 256);  add(dec_be, O_DBE, 256);  add(dec_b2, O_DB2, 2);
    add(dec_w2, O_DW2, 512);
    add(edge_b, O_EB, NL_ * 256); add(edge_g, O_EG, NL_ * 256); add(edge_be, O_EBE, NL_ * 256);
    add(node_b1, O_NB1, NL_ * 256); add(node_g, O_NG, NL_ * 256); add(node_be, O_NBE, NL_ * 256);
    add(node_b2, O_NB2, NL_ * 256);
    add(grid_w1, O_GW1, 512);
    cm.cnt = i;
    cvt_many_k<<<dim3(6, cm.cnt), 256, 0, stream>>>(cm);
  }

  // ---- weight transposes (flag-aware src, bf16 N-major out) ----
  transpose_k<<<dim3(256, 1, 1), 256, 0, stream>>>(grid_w2, wt_grid_w2, 256, 256, 0, 0, dflag);
  transpose_k<<<dim3(288, 1, 1), 256, 0, stream>>>(comb_w1, wt_comb_w1, 259, 288, 0, 0, dflag);
  transpose_k<<<dim3(256, 1, 1), 256, 0, stream>>>(comb_w2, wt_comb_w2, 256, 256, 0, 0, dflag);
  transpose_k<<<dim3(256, 1, 1), 256, 0, stream>>>(dec_w1,  wt_dec_w1,  256, 256, 0, 0, dflag);
  transpose_k<<<dim3(544, 1, NL_), 256, 0, stream>>>(edge_w,  wt_edge,  516, 544, (long)516 * 256, (long)256 * 544, dflag);
  transpose_k<<<dim3(512, 1, NL_), 256, 0, stream>>>(node_w1, wt_node1, 512, 512, (long)512 * 256, (long)256 * 512, dflag);
  transpose_k<<<dim3(256, 1, NL_), 256, 0, stream>>>(node_w2, wt_node2, 256, 256, (long)256 * 256, (long)256 * 256, dflag);

  // ---- grid-encoder LN stats ----
  grid_stats_k<<<dim3((int)(BNG / 4)), 256, 0, stream>>>(c_gin, varena + O_GW1, varena + O_GB1, gstats, (int)BNG);

  // ---- grid encoder + g2m pooling, streamed per batch through gp_b ----
  for (int b = 0; b < B_; b++) {
    GemmP p{}; p.Wt = wt_grid_w2; p.bias = varena + O_GB2; p.Y = gp_b;
    p.gin = c_gin; p.gw1 = varena + O_GW1; p.gb1 = varena + O_GB1;
    p.gg = varena + O_GG; p.gbe = varena + O_GBE;
    p.stats = gstats; p.rowoff = (long)b * NG_;
    p.M = NG_; p.K = 256; p.Kpad = 256;
    gemm_k<A_GRID, E_STORE><<<dim3((NG_ + 63) / 64), 256, 0, stream>>>(p);
    g2m_b_k<<<dim3(NM_), 256, 0, stream>>>(gp_b, g2m_i, c_g2mw, pooled + (long)b * NM_ * 256);
  }

  // ---- comb MLP ----
  {
    GemmP p{}; p.A = pooled; p.mf = c_mf; p.Wt = wt_comb_w1; p.bias = varena + O_CB1;
    p.g = varena + O_CG; p.beta = varena + O_CBE; p.Y = t2; p.M = (int)BNM; p.K = 259; p.Kpad = 288;
    gemm_k<A_COMB, E_LN_STORE><<<dim3((int)((BNM + 63) / 64)), 256, 0, stream>>>(p);
  }
  const long n4 = BNM * 256 / 4;
  zero_f32_k<<<dim3((int)((n4 + 255) / 256)), 256, 0, stream>>>(xf32, n4);
  {
    GemmP p{}; p.A = t2; p.Wt = wt_comb_w2; p.bias = varena + O_CB2; p.xf32 = xf32;
    p.M = (int)BNM; p.K = 256; p.Kpad = 256;
    gemm_k<A_DIRECT, E_RESID><<<dim3((int)((BNM + 63) / 64)), 256, 0, stream>>>(p);
  }

  // ---- message-passing layers ----
  for (int l = 0; l < NL_; l++) {
    zero_f32_k<<<dim3((int)((n4 + 255) / 256)), 256, 0, stream>>>(agg, n4);
    {
      GemmP p{}; p.Ax = xf32; p.Wt = wt_edge + (size_t)l * 256 * 544;
      p.bias = varena + O_EB + l * 256; p.g = varena + O_EG + l * 256; p.beta = varena + O_EBE + l * 256;
      p.agg = agg; p.edst = edge_index + E_; p.esrc = edge_index; p.ea = c_ea;
      p.M = (int)BE; p.K = 516; p.Kpad = 544;
      gemm_k<A_EDGE, E_LN_SCATTER><<<dim3((int)(BE / 64)), 256, 0, stream>>>(p);
    }
    {
      GemmP p{}; p.Ax = xf32; p.Aagg = agg; p.Wt = wt_node1 + (size_t)l * 256 * 512;
      p.bias = varena + O_NB1 + l * 256; p.g = varena + O_NG + l * 256; p.beta = varena + O_NBE + l * 256;
      p.Y = t2; p.M = (int)BNM; p.K = 512; p.Kpad = 512;
      gemm_k<A_NODE1, E_LN_STORE><<<dim3((int)((BNM + 63) / 64)), 256, 0, stream>>>(p);
    }
    {
      GemmP p{}; p.A = t2; p.Wt = wt_node2 + (size_t)l * 256 * 256;
      p.bias = varena + O_NB2 + l * 256; p.xf32 = xf32;
      p.M = (int)BNM; p.K = 256; p.Kpad = 256;
      gemm_k<A_DIRECT, E_RESID><<<dim3((int)((BNM + 63) / 64)), 256, 0, stream>>>(p);
    }
  }

  // ---- m2g pooling + decoder (dec2 fused), streamed per batch; FLOAT32 output ----
  for (int b = 0; b < B_; b++) {
    m2g_b_k<<<dim3(NG_), 256, 0, stream>>>(xf32 + (long)b * NM_ * 256, m2g_i, c_m2gw, glat_b);
    GemmP p{}; p.A = glat_b; p.Wt = wt_dec_w1; p.bias = varena + O_DB1;
    p.g = varena + O_DG; p.beta = varena + O_DBE;
    p.dw2 = varena + O_DW2; p.db2 = varena + O_DB2;
    p.out2 = (float*)d_out + (long)b * NG_ * 2;
    p.M = NG_; p.K = 256; p.Kpad = 256;
    gemm_k<A_DIRECT, E_LN_DEC><<<dim3((NG_ + 63) / 64), 256, 0, stream>>>(p);
  }
}